// Round 8
// baseline (359.604 us; speedup 1.0000x reference)
//
#include <hip/hip_runtime.h>
#include <math.h>

#define N_RES 768
#define DISTO_BINS 64
#define LDDT_BINS 50
#define DISTO_BLOCKS 2048
#define LDDT_BLOCKS N_RES
#define EXP_BLOCKS 64
#define TOTAL_BLOCKS (DISTO_BLOCKS + LDDT_BLOCKS + EXP_BLOCKS)
#define NPAIRS (N_RES * N_RES)
#define NCHUNKS (NPAIRS / 4)          /* 147456 = 8192 waves * 18 */
#define CHUNKS_PER_WAVE 18

// accumulator slots in ws (floats): 0=disto 1=lddt 2=expnum 3=expden
//                                   4=sum_pbm 5=sum_mask_ca 6=counter(bits)
typedef float f32x4 __attribute__((ext_vector_type(4)));

// 16-lane (DPP row) sum via row_ror rotations — pure VALU pipe.
#define ROW_ADD_ROR(v, N)                                                     \
    v += __int_as_float(__builtin_amdgcn_update_dpp(                          \
        0, __float_as_int(v), 0x120 | (N), 0xF, 0xF, false))

// ---------------- Kernel 0: init accumulators + tiny sums -------------------
__global__ __launch_bounds__(256)
void init_kernel(const float* __restrict__ pbm,      // (N,)
                 const float* __restrict__ mask37,   // (N,37)
                 float* __restrict__ a) {            // ws accumulators
    const int tid = threadIdx.x;
    if (tid < 8) a[tid] = 0.f;
    float sm = 0.f, smca = 0.f;
    for (int k = tid; k < N_RES; k += 256) {
        sm   += pbm[k];
        smca += mask37[k * 37 + 1];
    }
    __shared__ float r1[256], r2[256];
    r1[tid] = sm;
    r2[tid] = smca;
    __syncthreads();
    for (int s = 128; s > 0; s >>= 1) {
        if (tid < s) { r1[tid] += r1[tid + s]; r2[tid] += r2[tid + s]; }
        __syncthreads();
    }
    if (tid == 0) { a[4] = r1[0]; a[5] = r2[0]; }
}

// ---------------- Kernel 1: everything, one launch --------------------------
// blocks [0, DISTO_BLOCKS)               : distogram CE partial sums
// blocks [DISTO_BLOCKS, +N_RES)          : per-residue lddt + CE
// blocks [DISTO_BLOCKS+N_RES, +EXP)      : exp-resolved partial sums
// last block to finish combines accumulators -> out[0]
__global__ __launch_bounds__(256)
void main_kernel(const f32x4* __restrict__ logits4,
                 const float* __restrict__ pb,          // (N,3)
                 const float* __restrict__ pbm,         // (N,)
                 const float* __restrict__ pred37,      // (N,37,3)
                 const float* __restrict__ true37,      // (N,37,3)
                 const float* __restrict__ mask37,      // (N,37)
                 const float* __restrict__ lddt_logits, // (N,50)
                 const float* __restrict__ exl,         // (N,37)
                 const float* __restrict__ a37ex,       // (N,37)
                 const float* __restrict__ resolution,  // (1,)
                 float* __restrict__ a,                 // ws accumulators
                 float* __restrict__ out) {
    __shared__ float r1[256], r2[256];
    const int tid  = threadIdx.x;
    const int nthr = blockDim.x;

    if (blockIdx.x < DISTO_BLOCKS) {
        // ================= distogram partial sums =================
        __shared__ float spx[N_RES], spy[N_RES], spz[N_RES], spm[N_RES];
        for (int k = tid; k < N_RES; k += nthr) {
            spx[k] = pb[3 * k + 0];
            spy[k] = pb[3 * k + 1];
            spz[k] = pb[3 * k + 2];
            spm[k] = pbm[k];
        }
        __syncthreads();

        const int lane = tid & 63;
        const int wid  = tid >> 6;
        const int q    = lane >> 4;    // pair-group 0..3 within wave
        const int gl   = lane & 15;    // lane within group
        const int gw   = blockIdx.x * 4 + wid;          // wave id 0..8191
        const int base = gw * CHUNKS_PER_WAVE;          // contiguous 18 KB

        float acc = 0.f;

#define DISTO_PROC(xv4, cc)                                                   \
    {                                                                         \
        float e = __expf(xv4.x) + __expf(xv4.y) + __expf(xv4.z) +             \
                  __expf(xv4.w);                                              \
        ROW_ADD_ROR(e, 8);                                                    \
        ROW_ADD_ROR(e, 4);                                                    \
        ROW_ADD_ROR(e, 2);                                                    \
        ROW_ADD_ROR(e, 1);                                                    \
        int p = (cc) * 4 + q;                                                 \
        int i = p / N_RES;                                                    \
        int j = p - i * N_RES;                                                \
        float dx = spx[i] - spx[j];                                           \
        float dy = spy[i] - spy[j];                                           \
        float dz = spz[i] - spz[j];                                           \
        float d  = sqrtf(dx * dx + dy * dy + dz * dz);                        \
        float t  = ceilf((d - 2.3125f) * 3.2f);                               \
        int bin  = (int)fminf(fmaxf(t, 0.f), 63.f);                           \
        float w  = spm[i] * spm[j];                                           \
        float xs = (bin & 2) ? ((bin & 1) ? xv4.w : xv4.z)                    \
                             : ((bin & 1) ? xv4.y : xv4.x);                   \
        float lg = (gl == 0) ? w * __logf(e) : 0.f;                           \
        float bt = (gl == (bin >> 2)) ? w * xs : 0.f;                         \
        acc += lg - bt;                                                       \
    }

#pragma unroll
        for (int t3 = 0; t3 < 3; ++t3) {
            const int cb = base + t3 * 6;
            f32x4 x0 = __builtin_nontemporal_load(
                &logits4[(size_t)(cb + 0) * 64 + lane]);
            f32x4 x1 = __builtin_nontemporal_load(
                &logits4[(size_t)(cb + 1) * 64 + lane]);
            f32x4 x2 = __builtin_nontemporal_load(
                &logits4[(size_t)(cb + 2) * 64 + lane]);
            f32x4 x3 = __builtin_nontemporal_load(
                &logits4[(size_t)(cb + 3) * 64 + lane]);
            f32x4 x4 = __builtin_nontemporal_load(
                &logits4[(size_t)(cb + 4) * 64 + lane]);
            f32x4 x5 = __builtin_nontemporal_load(
                &logits4[(size_t)(cb + 5) * 64 + lane]);
            DISTO_PROC(x0, cb + 0);
            DISTO_PROC(x1, cb + 1);
            DISTO_PROC(x2, cb + 2);
            DISTO_PROC(x3, cb + 3);
            DISTO_PROC(x4, cb + 4);
            DISTO_PROC(x5, cb + 5);
        }
#undef DISTO_PROC

        acc += __shfl_xor(acc, 1, 64);
        acc += __shfl_xor(acc, 2, 64);
        acc += __shfl_xor(acc, 4, 64);
        acc += __shfl_xor(acc, 8, 64);
        acc += __shfl_xor(acc, 16, 64);
        acc += __shfl_xor(acc, 32, 64);
        if (lane == 0) r1[wid] = acc;
        __syncthreads();
        if (tid == 0)
            atomicAdd(&a[0], r1[0] + r1[1] + r1[2] + r1[3]);
    } else if (blockIdx.x >= DISTO_BLOCKS + LDDT_BLOCKS) {
        // ================= exp-resolved partial sums =================
        const int b = blockIdx.x - DISTO_BLOCKS - LDDT_BLOCKS;
        const int gid = b * nthr + tid;
        const int stride = EXP_BLOCKS * nthr;
        const int n = N_RES * 37;
        float num = 0.f, den = 0.f;
        for (int k = gid; k < n; k += stride) {
            float x  = exl[k];
            float m  = mask37[k];
            float ex = a37ex[k];
            float ax = fabsf(x);
            float sp = __logf(1.f + __expf(-ax));   // softplus(-|x|)
            float ls  = sp + fmaxf(-x, 0.f);        // -log_sigmoid(x)
            float lsn = sp + fmaxf(x, 0.f);         // -log_sigmoid(-x)
            float err = m * ls + (1.f - m) * lsn;
            num += err * ex;
            den += ex;
        }
        r1[tid] = num;
        r2[tid] = den;
        __syncthreads();
        for (int s = nthr >> 1; s > 0; s >>= 1) {
            if (tid < s) { r1[tid] += r1[tid + s]; r2[tid] += r2[tid + s]; }
            __syncthreads();
        }
        if (tid == 0) {
            atomicAdd(&a[2], r1[0]);
            atomicAdd(&a[3], r2[0]);
        }
    } else {
        // ================= per-residue lddt + CE =================
        const int i = blockIdx.x - DISTO_BLOCKS;
        const float tix = true37[(i * 37 + 1) * 3 + 0];
        const float tiy = true37[(i * 37 + 1) * 3 + 1];
        const float tiz = true37[(i * 37 + 1) * 3 + 2];
        const float pix = pred37[(i * 37 + 1) * 3 + 0];
        const float piy = pred37[(i * 37 + 1) * 3 + 1];
        const float piz = pred37[(i * 37 + 1) * 3 + 2];
        const float mi  = mask37[i * 37 + 1];

        float scope_sum = 0.f, score_sum = 0.f;
        for (int j = tid; j < N_RES; j += nthr) {
            float mj  = mask37[j * 37 + 1];
            float dtx = tix - true37[(j * 37 + 1) * 3 + 0];
            float dty = tiy - true37[(j * 37 + 1) * 3 + 1];
            float dtz = tiz - true37[(j * 37 + 1) * 3 + 2];
            float dt  = sqrtf(1e-10f + dtx * dtx + dty * dty + dtz * dtz);
            float dpx = pix - pred37[(j * 37 + 1) * 3 + 0];
            float dpy = piy - pred37[(j * 37 + 1) * 3 + 1];
            float dpz = piz - pred37[(j * 37 + 1) * 3 + 2];
            float dp  = sqrtf(1e-10f + dpx * dpx + dpy * dpy + dpz * dpz);
            float scope = (dt < 15.f && j != i) ? (mi * mj) : 0.f;
            float l1 = fabsf(dt - dp);
            float sc = 0.25f * ((l1 < 0.5f ? 1.f : 0.f) + (l1 < 1.f ? 1.f : 0.f) +
                                (l1 < 2.f ? 1.f : 0.f) + (l1 < 4.f ? 1.f : 0.f));
            scope_sum += scope;
            score_sum += scope * sc;
        }

        r1[tid] = scope_sum;
        r2[tid] = score_sum;
        __syncthreads();
        for (int s = nthr >> 1; s > 0; s >>= 1) {
            if (tid < s) { r1[tid] += r1[tid + s]; r2[tid] += r2[tid + s]; }
            __syncthreads();
        }

        __shared__ int binS;
        if (tid == 0) {
            float lddt = (1e-10f + r2[0]) / (1e-10f + r1[0]);
            int bin = (int)floorf(lddt * (float)LDDT_BINS);
            binS = min(max(bin, 0), LDDT_BINS - 1);
        }
        __syncthreads();

        float e = (tid < LDDT_BINS) ? __expf(lddt_logits[i * LDDT_BINS + tid]) : 0.f;
        r1[tid] = e;
        __syncthreads();
        for (int s = nthr >> 1; s > 0; s >>= 1) {
            if (tid < s) r1[tid] += r1[tid + s];
            __syncthreads();
        }
        if (tid == 0) {
            float err = __logf(r1[0]) - lddt_logits[i * LDDT_BINS + binS];
            atomicAdd(&a[1], err * mi);
        }
    }

    // ---------------- last-block-done final combine ----------------
    __syncthreads();
    if (tid == 0) {
        __threadfence();
        unsigned int* cnt = (unsigned int*)(a + 6);
        unsigned int old = atomicAdd(cnt, 1u);
        if (old == TOTAL_BLOCKS - 1) {
            // atomic reads hit the device coherent point (safe across XCD L2s)
            float sd   = atomicAdd(&a[0], 0.f);
            float se   = atomicAdd(&a[1], 0.f);
            float num  = atomicAdd(&a[2], 0.f);
            float den  = atomicAdd(&a[3], 0.f);
            float sm   = atomicAdd(&a[4], 0.f);
            float smca = atomicAdd(&a[5], 0.f);
            float res  = resolution[0];
            float gate = (res >= 0.1f && res <= 3.0f) ? 1.f : 0.f;
            float l_disto = sd / (1e-6f + sm * sm);
            float l_plddt = se / (1e-10f + smca) * gate;
            float l_exp   = num / (1e-8f + den) * gate;
            out[0] = 0.3f * l_disto + 0.01f * l_plddt + 0.01f * l_exp;
        }
    }
}

extern "C" void kernel_launch(void* const* d_in, const int* in_sizes, int n_in,
                              void* d_out, int out_size, void* d_ws, size_t ws_size,
                              hipStream_t stream) {
    const float* disto       = (const float*)d_in[0];  // (1,768,768,64)
    const float* pb          = (const float*)d_in[1];  // (1,768,3)
    const float* pbm         = (const float*)d_in[2];  // (1,768)
    const float* lddt_logits = (const float*)d_in[3];  // (1,768,50)
    const float* pred        = (const float*)d_in[4];  // (1,768,37,3)
    const float* truep       = (const float*)d_in[5];  // (1,768,37,3)
    const float* am          = (const float*)d_in[6];  // (1,768,37)
    const float* exl         = (const float*)d_in[7];  // (1,768,37)
    const float* a37         = (const float*)d_in[8];  // (1,768,37)
    const float* resolution  = (const float*)d_in[9];  // (1,)
    float* out = (float*)d_out;
    float* acc = (float*)d_ws;   // 8 floats: accumulators + counter

    init_kernel<<<1, 256, 0, stream>>>(pbm, am, acc);
    main_kernel<<<TOTAL_BLOCKS, 256, 0, stream>>>(
        (const f32x4*)disto, pb, pbm, pred, truep, am, lddt_logits,
        exl, a37, resolution, acc, out);
}